// Round 1
// baseline (96.864 us; speedup 1.0000x reference)
//
#include <hip/hip_runtime.h>
#include <hip/hip_bf16.h>

typedef unsigned short u16;
typedef unsigned int u32;

#define THREADS 256
constexpr int CH = 64;        // in/out channels
constexpr int PP = 32;        // neighbors per point
constexpr int TM = 16;        // points per block
constexpr int G16 = 16;       // kernel bins (4x4)

// ---- LDS layout (bytes) ----
constexpr int W_PSTRIDE = 40;                       // padded p-dim (keeps A-frag b128 16B-aligned, 2-way banks)
constexpr int W_MSTRIDE = G16 * W_PSTRIDE;          // 640 elems per point
constexpr int W_BYTES   = TM * W_MSTRIDE * 2;       // 20480
constexpr int RECV_OFF  = W_BYTES;                  // 20480
constexpr int RECV_BYTES = TM * PP * 4;             // 2048
constexpr int F_OFF     = RECV_OFF + RECV_BYTES;    // 22528
constexpr int F_PSTRIDE = 34;                       // padded p per channel row (2-way banks on b16 writes)
constexpr int F_PT      = CH * F_PSTRIDE;           // 2176 elems per point
constexpr int F_BYTES   = 8 * F_PT * 2;             // 34816
constexpr int MH_OFF    = F_OFF + F_BYTES;          // 57344
constexpr int MH_GSTRIDE = 144;                     // bytes per g-row (128 + 16 pad, 16B aligned)
constexpr int MH_NSTRIDE = G16 * MH_GSTRIDE + 16;   // 2320
constexpr int MH_BYTES  = 8 * MH_NSTRIDE;           // 18560
constexpr int LDS_BYTES = MH_OFF + MH_BYTES;        // 75904
static_assert(LDS_BYTES == 75904, "lds layout");

typedef __attribute__((ext_vector_type(8))) short short8;
typedef __attribute__((ext_vector_type(4))) float f32x4;

static __device__ __forceinline__ u16 f2bf(float f) {
  __hip_bfloat16 h = __float2bfloat16(f);
  return __builtin_bit_cast(u16, h);
}

// ---- prep 1: features f32 -> bf16 ----
__global__ void prep_feat(const float* __restrict__ in, u16* __restrict__ outb, int n2) {
  int i = blockIdx.x * blockDim.x + threadIdx.x;  // i indexes float2 pairs
  if (i < n2) {
    float2 v = ((const float2*)in)[i];
    u32 u = (u32)f2bf(v.x) | ((u32)f2bf(v.y) << 16);
    ((u32*)outb)[i] = u;
  }
}

// ---- prep 2: kernel f32 [g][i][o] -> bf16 in B-fragment order ----
// K2F[d], d = ((ks*4 + ot)*64 + lane)*8 + e ;  k = ks*32 + (lane>>4)*8 + e ; o = ot*16 + (lane&15)
__global__ void prep_k2f(const float* __restrict__ kern, u16* __restrict__ k2f) {
  int d = blockIdx.x * blockDim.x + threadIdx.x;   // 65536 total
  int e = d & 7, l = (d >> 3) & 63, ot = (d >> 9) & 3, ks = d >> 11;
  int k = ks * 32 + (l >> 4) * 8 + e;
  int o = ot * 16 + (l & 15);
  k2f[d] = f2bf(kern[k * 64 + o]);
}

// ---- main fused kernel: 16 points per block ----
__global__ __launch_bounds__(THREADS, 2) void cconv_main(
    const int* __restrict__ recv, const float* __restrict__ relpos,
    const float* __restrict__ wsup, const int* __restrict__ aptr,
    const u16* __restrict__ fbf, const u16* __restrict__ k2f,
    const float* __restrict__ bias, float* __restrict__ out) {
  extern __shared__ __align__(16) char smem[];
  u16* Wl = (u16*)smem;
  int* recvl = (int*)(smem + RECV_OFF);
  u16* Fl = (u16*)(smem + F_OFF);
  char* Mb = smem + MH_OFF;

  const int tid = threadIdx.x;
  const int n0 = blockIdx.x * TM;

  // ---- P0: per-edge window/bilinear weight columns into W, receivers into LDS ----
  {
    const float invws = 1.0f / wsup[0];
    int a = aptr[0];
    if (a < 0 || a > 64) a = (int)(*(const float*)aptr);  // dtype fallback
    #pragma unroll
    for (int ee = 0; ee < 2; ++ee) {
      const int e = tid + ee * 256;
      const int m = e >> 5, p = e & 31;
      const int ei = (n0 + m) * PP + p;
      recvl[e] = recv[ei];
      const float rx = relpos[2 * ei + 0] * invws;
      const float ry = relpos[2 * ei + 1] * invws;
      const float d2 = rx * rx + ry * ry;
      const float w1 = fmaxf(1.0f - d2, 0.0f);
      float win = 1.0f;
      for (int q = 0; q < a; ++q) win *= w1;
      float gy = (rx + 1.0f) * 1.5f; gy = fminf(fmaxf(gy, 0.0f), 3.0f);
      float gx = (ry + 1.0f) * 1.5f; gx = fminf(fmaxf(gx, 0.0f), 3.0f);
      int y0 = (int)floorf(gy); y0 = y0 < 0 ? 0 : (y0 > 2 ? 2 : y0);
      int x0 = (int)floorf(gx); x0 = x0 < 0 ? 0 : (x0 > 2 ? 2 : x0);
      const float fy = gy - (float)y0, fx = gx - (float)x0;
      float wy[4], wx[4];
      #pragma unroll
      for (int y = 0; y < 4; ++y)
        wy[y] = win * ((y == y0) ? (1.0f - fy) : (y == y0 + 1) ? fy : 0.0f);
      #pragma unroll
      for (int x = 0; x < 4; ++x)
        wx[x] = (x == x0) ? (1.0f - fx) : (x == x0 + 1) ? fx : 0.0f;
      u16* wp = Wl + m * W_MSTRIDE + p;
      #pragma unroll
      for (int y = 0; y < 4; ++y)
        #pragma unroll
        for (int x = 0; x < 4; ++x)
          wp[(y * 4 + x) * W_PSTRIDE] = f2bf(wy[y] * wx[x]);
    }
  }
  __syncthreads();

  const int wid = tid >> 6, lane = tid & 63;
  const int l15 = lane & 15, l4 = lane >> 4;
  f32x4 acc2 = {0.f, 0.f, 0.f, 0.f};
  const short8 z8 = {};

  #pragma unroll
  for (int h = 0; h < 2; ++h) {
    // ---- gather: 256 edges (8 points) -> F_T[pt][ch][p] bf16 ----
    {
      const int rvv = recvl[h * 256 + wid * 64 + lane];  // 64 receiver ids for this wave
      #pragma unroll 16
      for (int j = 0; j < 64; ++j) {
        const int rv = __builtin_amdgcn_readlane(rvv, j);
        const int eh = wid * 64 + j;
        Fl[(eh >> 5) * F_PT + lane * F_PSTRIDE + (eh & 31)] = fbf[rv * CH + lane];
      }
    }
    __syncthreads();
    // ---- build M (2 points per wave): M[16g x 64i] = W[16g x 32p] @ F[32p x 64i] ----
    #pragma unroll
    for (int t = 0; t < 2; ++t) {
      const int mloc = wid * 2 + t;   // 0..7
      const int m = h * 8 + mloc;     // 0..15
      const short8 af = *(const short8*)((const char*)Wl +
          (m * W_MSTRIDE + l15 * W_PSTRIDE) * 2 + l4 * 16);
      f32x4 accm[4];
      #pragma unroll
      for (int ib = 0; ib < 4; ++ib) {
        const u32* fp = (const u32*)((const char*)Fl +
            (mloc * F_PT + (ib * 16 + l15) * F_PSTRIDE) * 2 + l4 * 16);
        union { u32 u[4]; short8 s; } bb;
        bb.u[0] = fp[0]; bb.u[1] = fp[1]; bb.u[2] = fp[2]; bb.u[3] = fp[3];
        f32x4 cz = {0.f, 0.f, 0.f, 0.f};
        accm[ib] = __builtin_amdgcn_mfma_f32_16x16x32_bf16(af, bb.s, cz, 0, 0, 0);
      }
      // stage M as bf16: rows g = 4*l4 + r, col i = ib*16 + l15
      #pragma unroll
      for (int ib = 0; ib < 4; ++ib)
        #pragma unroll
        for (int r = 0; r < 4; ++r) {
          const int g = l4 * 4 + r;
          const int i = ib * 16 + l15;
          *(u16*)(Mb + mloc * MH_NSTRIDE + g * MH_GSTRIDE + i * 2) = f2bf(accm[ib][r]);
        }
    }
    __syncthreads();
    // ---- half GEMM2: out[16n x 16o per wave] += Mh[8n x 1024k] @ K2[1024k x 64o] ----
    {
      const int krow = l15;
      const bool valid = (h == 0) ? (krow < 8) : (krow >= 8);
      const int nloc = krow & 7;
      #pragma unroll 8
      for (int ks = 0; ks < 32; ++ks) {
        const int kc = ks * 32 + l4 * 8;
        const int g = kc >> 6, ii = kc & 63;
        short8 a2 = *(const short8*)(Mb + nloc * MH_NSTRIDE + g * MH_GSTRIDE + ii * 2);
        a2 = valid ? a2 : z8;
        const short8 b2 = *(const short8*)(k2f + ((ks * 4 + wid) * 64 + lane) * 8);
        acc2 = __builtin_amdgcn_mfma_f32_16x16x32_bf16(a2, b2, acc2, 0, 0, 0);
      }
    }
    // no barrier needed here: next gather writes only F; the post-gather barrier
    // fences this GEMM's Mh reads before build(h=1) overwrites Mh.
  }
  // ---- epilogue: D rows n = 4*l4 + r, col o = wid*16 + l15 ----
  const int o = wid * 16 + l15;
  const float bv = bias[o];
  #pragma unroll
  for (int r = 0; r < 4; ++r) {
    const int n = l4 * 4 + r;
    out[(n0 + n) * CH + o] = acc2[r] * (1.0f / 32.0f) + bv;
  }
}

extern "C" void kernel_launch(void* const* d_in, const int* in_sizes, int n_in,
                              void* d_out, int out_size, void* d_ws, size_t ws_size,
                              hipStream_t stream) {
  const float* features = (const float*)d_in[0];
  const int* receivers  = (const int*)d_in[1];
  const float* relpos   = (const float*)d_in[2];
  const float* wsup     = (const float*)d_in[3];
  const int* aptr       = (const int*)d_in[4];
  const float* kern     = (const float*)d_in[5];
  const float* bias     = (const float*)d_in[6];
  float* out = (float*)d_out;

  const int N = in_sizes[0] / CH;   // 50000
  u16* fbf = (u16*)d_ws;                                    // N*64 bf16 = 6.4 MB
  u16* k2f = (u16*)((char*)d_ws + (size_t)N * CH * 2);      // 128 KB, frag-ordered

  const int nfeat2 = in_sizes[0] / 2;
  prep_feat<<<dim3((nfeat2 + 255) / 256), dim3(256), 0, stream>>>(features, fbf, nfeat2);
  prep_k2f<<<dim3(65536 / 256), dim3(256), 0, stream>>>(kern, k2f);

  hipFuncSetAttribute((const void*)cconv_main,
                      hipFuncAttributeMaxDynamicSharedMemorySize, LDS_BYTES);
  cconv_main<<<dim3(N / TM), dim3(THREADS), LDS_BYTES, stream>>>(
      receivers, relpos, wsup, aptr, fbf, k2f, bias, out);
}

// Round 2
// 78.356 us; speedup vs baseline: 1.2362x; 1.2362x over previous
//
#include <hip/hip_runtime.h>
#include <hip/hip_bf16.h>

typedef unsigned short u16;
typedef unsigned int u32;

#define THREADS 256
constexpr int CH = 64;        // in/out channels
constexpr int PP = 32;        // neighbors per point
constexpr int TM = 16;        // points per block
constexpr int G16 = 16;       // kernel bins (4x4)

// ---- LDS layout ----
constexpr int PRM_BYTES = TM * PP * 16;            // 8192: per-edge {fy,fx,win,y0x0}
constexpr int MH_OFF    = PRM_BYTES;
constexpr int MH_GSTRIDE = 144;                    // 128 + 16 pad (16B aligned)
constexpr int MH_NSTRIDE = G16 * MH_GSTRIDE + 16;  // 2320
constexpr int MH_BYTES  = 8 * MH_NSTRIDE;          // 18560
constexpr int LDS_BYTES = MH_OFF + MH_BYTES;       // 26752 -> 5 blocks/CU
static_assert(LDS_BYTES == 26752, "lds layout");

typedef __attribute__((ext_vector_type(8))) short short8;
typedef __attribute__((ext_vector_type(4))) float f32x4;

static __device__ __forceinline__ u16 f2bf_rne(float f) {
  __hip_bfloat16 h = __float2bfloat16(f);
  return __builtin_bit_cast(u16, h);
}
static __device__ __forceinline__ u16 rbf(float f) {  // cheap round-half-up (2 VALU)
  u32 u = __builtin_bit_cast(u32, f);
  return (u16)((u + 0x8000u) >> 16);
}

// ---- prep 1: features f32 -> bf16 ----
__global__ void prep_feat(const float* __restrict__ in, u16* __restrict__ outb, int n2) {
  int i = blockIdx.x * blockDim.x + threadIdx.x;
  if (i < n2) {
    float2 v = ((const float2*)in)[i];
    u32 u = (u32)f2bf_rne(v.x) | ((u32)f2bf_rne(v.y) << 16);
    ((u32*)outb)[i] = u;
  }
}

// ---- prep 2: kernel f32 [g][i][o] -> bf16 in B-fragment order ----
__global__ void prep_k2f(const float* __restrict__ kern, u16* __restrict__ k2f) {
  int d = blockIdx.x * blockDim.x + threadIdx.x;   // 65536 total
  int e = d & 7, l = (d >> 3) & 63, ot = (d >> 9) & 3, ks = d >> 11;
  int k = ks * 32 + (l >> 4) * 8 + e;
  int o = ot * 16 + (l & 15);
  k2f[d] = f2bf_rne(kern[k * 64 + o]);
}

// ---- main fused kernel: 16 points per block, 4 waves ----
__global__ __launch_bounds__(THREADS, 5) void cconv_main(
    const int* __restrict__ recv, const float* __restrict__ relpos,
    const float* __restrict__ wsup, const int* __restrict__ aptr,
    const u16* __restrict__ fbf, const u16* __restrict__ k2f,
    const float* __restrict__ bias, float* __restrict__ out) {
  __shared__ __align__(16) char smem[LDS_BYTES];
  char* Pb = smem;            // params
  char* Mb = smem + MH_OFF;   // staged M half (8 points)

  const int tid = threadIdx.x;
  const int n0 = blockIdx.x * TM;

  // ---- P0: per-edge params {fy, fx, win, y0|x0<<2} into LDS (XOR-swizzled slots) ----
  {
    const float invws = 1.0f / wsup[0];
    int a = aptr[0];
    if (a < 0 || a > 64) a = (int)(*(const float*)aptr);  // dtype fallback
    #pragma unroll
    for (int ee = 0; ee < 2; ++ee) {
      const int e = tid + ee * 256;
      const int m = e >> 5, p = e & 31;
      const int ei = (n0 + m) * PP + p;
      const float2 rp2 = ((const float2*)relpos)[ei];
      const float rx = rp2.x * invws, ry = rp2.y * invws;
      const float d2 = rx * rx + ry * ry;
      const float w1 = fmaxf(1.0f - d2, 0.0f);
      float win = 1.0f;
      for (int q = 0; q < a; ++q) win *= w1;
      float gy = fminf(fmaxf((rx + 1.0f) * 1.5f, 0.0f), 3.0f);
      float gx = fminf(fmaxf((ry + 1.0f) * 1.5f, 0.0f), 3.0f);
      int y0 = (int)gy; y0 = y0 > 2 ? 2 : y0;
      int x0 = (int)gx; x0 = x0 > 2 ? 2 : x0;
      float4 pv;
      pv.x = gy - (float)y0;
      pv.y = gx - (float)x0;
      pv.z = win;
      pv.w = __builtin_bit_cast(float, (u32)(y0 | (x0 << 2)));
      const int slot = m * 32 + (p ^ ((p >> 3) & 3));   // bank-spread for frag reads
      *(float4*)(Pb + slot * 16) = pv;
    }
  }
  __syncthreads();

  const int wid = tid >> 6, lane = tid & 63;
  const int l15 = lane & 15, l4 = lane >> 4;
  const int gy_ = l15 >> 2, gx_ = l15 & 3;   // this lane's kernel bin (g = l15)
  f32x4 acc2 = {0.f, 0.f, 0.f, 0.f};
  const short8 z8 = {};

  for (int h = 0; h < 2; ++h) {
    // ---- build M for 8 points (2 per wave), gather direct-to-fragment ----
    #pragma unroll
    for (int t = 0; t < 2; ++t) {
      const int m = h * 8 + wid * 2 + t;
      // receiver ids for this lane's 8 edges: p = l4*8 + e (16-lane broadcast, coalesced)
      const int* rp = recv + (n0 + m) * PP + l4 * 8;
      const int4 ra = *(const int4*)rp;
      const int4 rb_ = *(const int4*)(rp + 4);
      const int rv[8] = {ra.x, ra.y, ra.z, ra.w, rb_.x, rb_.y, rb_.z, rb_.w};
      // A fragment: weight W[g=l15][p=l4*8+e] computed from params
      union { u16 h16[8]; short8 s; } au;
      #pragma unroll
      for (int e = 0; e < 8; ++e) {
        const int slot = m * 32 + l4 * 8 + (e ^ l4);
        const float4 pr = *(const float4*)(Pb + slot * 16);
        const u32 yx = __builtin_bit_cast(u32, pr.w);
        const int y0 = yx & 3, x0 = (yx >> 2) & 3;
        const float wy = (gy_ == y0) ? (1.0f - pr.x) : ((gy_ == y0 + 1) ? pr.x : 0.0f);
        const float wx = (gx_ == x0) ? (1.0f - pr.y) : ((gx_ == x0 + 1) ? pr.y : 0.0f);
        au.h16[e] = rbf(pr.z * wy * wx);
      }
      // B fragments straight from global: q[e] = fbf[rv[e]*64 + ib*16 + l15]
      u32 vo[8];
      #pragma unroll
      for (int e = 0; e < 8; ++e) vo[e] = (u32)rv[e] * 64u + (u32)l15;
      f32x4 accm[4];
      #pragma unroll
      for (int ib = 0; ib < 4; ++ib) {
        u32 q[8];
        #pragma unroll
        for (int e = 0; e < 8; ++e) q[e] = (u32)fbf[vo[e] + ib * 16];
        union { u32 u[4]; short8 s; } bb;
        #pragma unroll
        for (int j = 0; j < 4; ++j) bb.u[j] = q[2 * j] | (q[2 * j + 1] << 16);
        const f32x4 cz = {0.f, 0.f, 0.f, 0.f};
        accm[ib] = __builtin_amdgcn_mfma_f32_16x16x32_bf16(au.s, bb.s, cz, 0, 0, 0);
      }
      // stage M as bf16: rows g = l4*4 + r, col i = ib*16 + l15
      const int mloc = wid * 2 + t;
      #pragma unroll
      for (int ib = 0; ib < 4; ++ib)
        #pragma unroll
        for (int r = 0; r < 4; ++r)
          *(u16*)(Mb + mloc * MH_NSTRIDE + (l4 * 4 + r) * MH_GSTRIDE + (ib * 16 + l15) * 2)
              = rbf(accm[ib][r]);
    }
    __syncthreads();
    // ---- half GEMM2: acc[16n x 16o per wave] += Mh[8n x 1024k] @ K2[1024k x 64o] ----
    {
      const bool valid = (h == 0) ? (l15 < 8) : (l15 >= 8);
      const int nloc = l15 & 7;
      #pragma unroll 8
      for (int ks = 0; ks < 32; ++ks) {
        const int kc = ks * 32 + l4 * 8;
        const int g = kc >> 6, ii = kc & 63;
        short8 a2 = *(const short8*)(Mb + nloc * MH_NSTRIDE + g * MH_GSTRIDE + ii * 2);
        a2 = valid ? a2 : z8;
        const short8 b2 = *(const short8*)(k2f + ((ks * 4 + wid) * 64 + lane) * 8);
        acc2 = __builtin_amdgcn_mfma_f32_16x16x32_bf16(a2, b2, acc2, 0, 0, 0);
      }
    }
    if (h == 0) __syncthreads();   // protect Mb before next build overwrites it
  }
  // ---- epilogue: D rows n = l4*4 + r, col o = wid*16 + l15 ----
  const int o = wid * 16 + l15;
  const float bv = bias[o];
  #pragma unroll
  for (int r = 0; r < 4; ++r)
    out[(n0 + l4 * 4 + r) * CH + o] = acc2[r] * (1.0f / 32.0f) + bv;
}

extern "C" void kernel_launch(void* const* d_in, const int* in_sizes, int n_in,
                              void* d_out, int out_size, void* d_ws, size_t ws_size,
                              hipStream_t stream) {
  const float* features = (const float*)d_in[0];
  const int* receivers  = (const int*)d_in[1];
  const float* relpos   = (const float*)d_in[2];
  const float* wsup     = (const float*)d_in[3];
  const int* aptr       = (const int*)d_in[4];
  const float* kern     = (const float*)d_in[5];
  const float* bias     = (const float*)d_in[6];
  float* out = (float*)d_out;

  const int N = in_sizes[0] / CH;   // 50000
  u16* fbf = (u16*)d_ws;                                    // N*64 bf16 = 6.4 MB
  u16* k2f = (u16*)((char*)d_ws + (size_t)N * CH * 2);      // 128 KB, frag-ordered

  const int nfeat2 = in_sizes[0] / 2;
  prep_feat<<<dim3((nfeat2 + 255) / 256), dim3(256), 0, stream>>>(features, fbf, nfeat2);
  prep_k2f<<<dim3(65536 / 256), dim3(256), 0, stream>>>(kern, k2f);

  cconv_main<<<dim3(N / TM), dim3(THREADS), 0, stream>>>(
      receivers, relpos, wsup, aptr, fbf, k2f, bias, out);
}